// Round 2
// baseline (873.198 us; speedup 1.0000x reference)
//
#include <hip/hip_runtime.h>
#include <cstdint>
#include <cstddef>

#define ROW 963  // 3 coords + 64 + 128 + 256 + 512 channels

typedef float f32x4 __attribute__((ext_vector_type(4)));

__device__ __forceinline__ float bf2f(unsigned short u) {
    return __uint_as_float(((unsigned int)u) << 16);
}
__device__ __forceinline__ unsigned short f2bf(float v) {
    unsigned int u = __float_as_uint(v);
    // round-to-nearest-even
    u += 0x7FFFu + ((u >> 16) & 1u);
    return (unsigned short)(u >> 16);
}

// LDS row layout: logical out-float f (0..962) lives at index f for f<3
// (coords) and f+1 for f>=3 (channels). The +1 shift makes each thread's
// 4 channel values land at a 16B-aligned LDS offset -> single ds_write_b128.
// Byte offsets are XOR-swizzled (bits[4:5] ^= bits[7:8]) so that the
// stride-16B access patterns on BOTH sides are bank-conflict-free
// (lanes t,t+8 differ in byte bit7 -> swizzled bank-group bit4 differs).
__device__ __forceinline__ int lds_sw(int byte) {
    return byte ^ (((byte >> 7) & 3) << 4);
}
__device__ __forceinline__ float lds_get(const float* row, int f) {
    int byte = ((f < 3) ? f : f + 1) * 4;
    return *(const float*)((const char*)row + lds_sw(byte));
}

// Fused NCHW fp32 -> NHWC bf16 for all 4 pyramid levels.
// Thread indexes the OUTPUT (NHWC) element: 2B bf16 writes fully coalesced;
// fp32 reads are stride-SS gathers absorbed by L1/L2 (levels are MB-scale).
// NORMAL (caching) stores on purpose: proj re-reads these tables from L2.
// Level boundaries 200704/301056/351232 are multiples of 64 -> wave-uniform.
__global__ __launch_bounds__(256) void trans_all_k(
    const float* __restrict__ f1, const float* __restrict__ f2,
    const float* __restrict__ f3, const float* __restrict__ f4,
    unsigned short* __restrict__ o1, unsigned short* __restrict__ o2,
    unsigned short* __restrict__ o3, unsigned short* __restrict__ o4) {
    int r = blockIdx.x * 256 + threadIdx.x;
    int b = blockIdx.y;
    const float* src; unsigned short* dst; int SS, rr, lc;
    if (r < 200704)      { src = f1; dst = o1; SS = 3136; rr = r;          lc = 6; }
    else if (r < 301056) { src = f2; dst = o2; SS = 784;  rr = r - 200704; lc = 7; }
    else if (r < 351232) { src = f3; dst = o3; SS = 196;  rr = r - 301056; lc = 8; }
    else                 { src = f4; dst = o4; SS = 49;   rr = r - 351232; lc = 9; }
    int C  = 1 << lc;
    int c  = rr & (C - 1);   // channel (fast-varying -> coalesced writes)
    int sp = rr >> lc;       // spatial index i*S + j
    float v = src[(size_t)b * ((size_t)C * SS) + (size_t)c * SS + sp];
    dst[(size_t)b * ((size_t)SS * C) + rr] = f2bf(v);
}

// v3 projection kernel.
//  - v2 structure kept: grid-stride over points (2048 blocks = 8 blocks/CU),
//    geometry + bilinear weights computed once per point, all B batches inside.
//  - NEW: LDS-staged row + ALIGNMENT-FIXED store. orow = (b*N+n)*963 is only
//    4B-aligned, so direct per-thread stores degrade to 4x store_dword at 16B
//    lane stride = partial-line writes (32B of each 128B line per instr) ->
//    write-allocate RMW fetches from HBM. Here threads 0..239 each store one
//    16B-aligned float4 (stride-1 across lanes = 1024B fully-covered per
//    wave-instr, full-line writes), threads 240..245 mop up the <=3 lead and
//    <=3 tail floats of the row.
//  - nontemporal output stores: 770MB stream must not evict the 3MB bf16
//    tables from L2 (gathers re-read them ~500x).
__global__ __launch_bounds__(256) void proj_bf16_k(
    const float* __restrict__ coord,  // [N,3], batch-0 coords shared across b
    const unsigned short* __restrict__ t1, const unsigned short* __restrict__ t2,
    const unsigned short* __restrict__ t3, const unsigned short* __restrict__ t4,
    float* __restrict__ out, int N, int B) {
    int t = threadIdx.x;

    __shared__ float row[976];  // 964 floats + XOR-swizzle slack (<=971)

    // per-thread static geometry (loop-invariant)
    const unsigned short* T; int S, C, cs;
    if (t < 16)       { T = t1; S = 56; C = 64;  cs = 0; }
    else if (t < 48)  { T = t2; S = 28; C = 128; cs = 16; }
    else if (t < 112) { T = t3; S = 14; C = 256; cs = 48; }
    else              { T = t4; S = 7;  C = 512; cs = 112; }
    int cc = (t - cs) * 4;  // channel within level, multiple of 4 -> 8B aligned
    float scale = (float)S * (1.0f / 224.0f);  // exact power-of-two mul
    float sm1 = (float)(S - 1);
    size_t lvl = (size_t)(S * S) * C;          // per-batch elements of my level
    bool active = (t < 240);

    for (int n = blockIdx.x; n < N; n += gridDim.x) {
        float X = coord[3 * n + 0];
        float Y = coord[3 * n + 1];
        float Z = coord[3 * n + 2];
        // exact same fp32 op sequence as the reference
        float h = fminf(fmaxf((250.0f * -Y) / (-Z) + 112.0f, 0.0f), 223.0f);
        float w = fminf(fmaxf((250.0f * X) / (-Z) + 112.0f, 0.0f), 223.0f);
        float x = fminf(fmaxf(h * scale, 0.0f), sm1);
        float y = fminf(fmaxf(w * scale, 0.0f), sm1);
        float x1f = floorf(x), x2f = ceilf(x);
        float y1f = floorf(y), y2f = ceilf(y);
        int x1 = (int)x1f, x2 = (int)x2f;
        int y1 = (int)y1f, y2 = (int)y2f;
        float dx1 = x - x1f, dx2 = x2f - x;
        float dy1 = y - y1f, dy2 = y2f - y;
        float w11 = dx2 * dy2, w21 = dx1 * dy2, w12 = dx2 * dy1, w22 = dx1 * dy1;
        // element offsets within one batch's level table (no deref for t>=240)
        int i11 = (x1 * S + y1) * C + cc;
        int i12 = (x1 * S + y2) * C + cc;
        int i21 = (x2 * S + y1) * C + cc;
        int i22 = (x2 * S + y2) * C + cc;

        for (int b = 0; b < B; ++b) {
            // ---- compute phase: fill LDS row ----
            if (active) {
                const unsigned short* base = T + (size_t)b * lvl;
                ushort4 q11 = *(const ushort4*)(base + i11);
                ushort4 q12 = *(const ushort4*)(base + i12);
                ushort4 q21 = *(const ushort4*)(base + i21);
                ushort4 q22 = *(const ushort4*)(base + i22);
                f32x4 v;
                v.x = w11 * bf2f(q11.x) + w21 * bf2f(q21.x) + w12 * bf2f(q12.x) + w22 * bf2f(q22.x);
                v.y = w11 * bf2f(q11.y) + w21 * bf2f(q21.y) + w12 * bf2f(q12.y) + w22 * bf2f(q22.y);
                v.z = w11 * bf2f(q11.z) + w21 * bf2f(q21.z) + w12 * bf2f(q12.z) + w22 * bf2f(q22.z);
                v.w = w11 * bf2f(q11.w) + w21 * bf2f(q21.w) + w12 * bf2f(q12.w) + w22 * bf2f(q22.w);
                // channel floats 3+4t..3+4t+3 live at LDS idx 4+4t (16B aligned)
                int byte = 16 + 16 * t;
                *(f32x4*)((char*)row + lds_sw(byte)) = v;   // ds_write_b128
            } else if (t == 253) row[0] = X;   // lds_sw is identity for byte<16
            else if   (t == 254) row[1] = Y;
            else if   (t == 255) row[2] = Z;
            __syncthreads();

            // ---- copy phase: alignment-fixed, full-line stores ----
            size_t orow = ((size_t)b * N + n) * ROW;
            int lead = (4 - (int)(orow & 3)) & 3;   // floats to 16B boundary
            if (t < 240) {
                int f = lead + 4 * t;               // out[orow+f] is 16B aligned
                f32x4 v;
                v.x = lds_get(row, f + 0);
                v.y = lds_get(row, f + 1);
                v.z = lds_get(row, f + 2);
                v.w = lds_get(row, f + 3);
                __builtin_nontemporal_store(v, (f32x4*)(out + orow + f));
            } else if (t < 243) {                   // lead floats [0, lead)
                int j = t - 240;
                if (j < lead) out[orow + j] = lds_get(row, j);
            } else if (t < 246) {                   // tail floats [lead+960, 963)
                int j = t - 243;
                if (j < 3 - lead) {
                    int f = lead + 960 + j;
                    out[orow + f] = lds_get(row, f);
                }
            }
            __syncthreads();   // row reused by next (n,b)
        }
    }
}

// Fallback: direct NCHW fp32 gather (only if d_ws is too small -- not expected).
__global__ __launch_bounds__(256) void proj_nchw_k(
    const float* __restrict__ coord,
    const float* __restrict__ f1, const float* __restrict__ f2,
    const float* __restrict__ f3, const float* __restrict__ f4,
    float* __restrict__ out, int N) {
    int n = blockIdx.x, b = blockIdx.y;
    float X = coord[3 * n + 0], Y = coord[3 * n + 1], Z = coord[3 * n + 2];
    float h = fminf(fmaxf((250.0f * -Y) / (-Z) + 112.0f, 0.0f), 223.0f);
    float w = fminf(fmaxf((250.0f * X) / (-Z) + 112.0f, 0.0f), 223.0f);
    size_t orow = ((size_t)b * N + n) * ROW;
    if (threadIdx.x < 3) out[orow + threadIdx.x] = coord[3 * n + threadIdx.x];
    for (int c = threadIdx.x; c < 960; c += 256) {
        const float* T; int S, C, cc;
        if (c < 64)       { T = f1; S = 56; C = 64;  cc = c; }
        else if (c < 192) { T = f2; S = 28; C = 128; cc = c - 64; }
        else if (c < 448) { T = f3; S = 14; C = 256; cc = c - 192; }
        else              { T = f4; S = 7;  C = 512; cc = c - 448; }
        float scale = (float)S * (1.0f / 224.0f);
        float sm1 = (float)(S - 1);
        float x = fminf(fmaxf(h * scale, 0.0f), sm1);
        float y = fminf(fmaxf(w * scale, 0.0f), sm1);
        float x1f = floorf(x), x2f = ceilf(x);
        float y1f = floorf(y), y2f = ceilf(y);
        int x1 = (int)x1f, x2 = (int)x2f, y1 = (int)y1f, y2 = (int)y2f;
        const float* base = T + ((size_t)b * C + cc) * (size_t)(S * S);
        float Q11 = base[x1 * S + y1], Q12 = base[x1 * S + y2];
        float Q21 = base[x2 * S + y1], Q22 = base[x2 * S + y2];
        float dx1 = x - x1f, dx2 = x2f - x, dy1 = y - y1f, dy2 = y2f - y;
        out[orow + 3 + c] = (dx2 * dy2) * Q11 + (dx1 * dy2) * Q21 +
                            (dx2 * dy1) * Q12 + (dx1 * dy1) * Q22;
    }
}

extern "C" void kernel_launch(void* const* d_in, const int* in_sizes, int n_in,
                              void* d_out, int out_size, void* d_ws, size_t ws_size,
                              hipStream_t stream) {
    const float* inputs = (const float*)d_in[0];  // [B,N,3]; batch 0 = coords
    const float* f1 = (const float*)d_in[1];      // [B,64,56,56]
    const float* f2 = (const float*)d_in[2];      // [B,128,28,28]
    const float* f3 = (const float*)d_in[3];      // [B,256,14,14]
    const float* f4 = (const float*)d_in[4];      // [B,512,7,7]
    float* out = (float*)d_out;

    int B = in_sizes[1] / (64 * 56 * 56);
    int N = in_sizes[0] / (B * 3);

    size_t n1 = (size_t)B * 200704;  // per-level bf16 element counts
    size_t n2 = (size_t)B * 100352;
    size_t n3 = (size_t)B * 50176;
    size_t n4 = (size_t)B * 25088;
    size_t need = (n1 + n2 + n3 + n4) * sizeof(unsigned short);

    dim3 blk(256);
    if (ws_size >= need) {
        unsigned short* o1 = (unsigned short*)d_ws;
        unsigned short* o2 = o1 + n1;
        unsigned short* o3 = o2 + n2;
        unsigned short* o4 = o3 + n3;
        trans_all_k<<<dim3(376320 / 256, B), blk, 0, stream>>>(
            f1, f2, f3, f4, o1, o2, o3, o4);
        // 2048 blocks x 4 waves = 8 blocks/CU (LDS 3.9KB/block, wave-slot bound)
        int nblk = N < 2048 ? N : 2048;
        proj_bf16_k<<<dim3(nblk), blk, 0, stream>>>(inputs, o1, o2, o3, o4, out, N, B);
    } else {
        proj_nchw_k<<<dim3(N, B), blk, 0, stream>>>(inputs, f1, f2, f3, f4, out, N);
    }
}